// Round 1
// 147.089 us; speedup vs baseline: 1.0367x; 1.0367x over previous
//
#include <hip/hip_runtime.h>

// Problem: B=8, H=W=1024, N=4096 matches, R=8 -> d=17, patch=289, out (B,N,578) f32.
// p[b,n,j] = img[b, m_y + j%17 - 8, m_x + j/17 - 8]   (zero-pad OOB)
// normalize each 289-vector: (p - mean) / (std_ddof1 + 1e-4)
//
// Key layout fact: the FAST output index j walks down image ROWS (stride 4KB).
// Gathering in output order makes every lane hit a different cache line.
// Instead: gather in image-row order (coalesced), reduce (order-independent),
// stage through LDS, read back transposed, write coalesced in output order.

#define IMG_H 1024
#define IMG_W 1024
#define DPATCH 17
#define NPATCH 289
#define RAD 8

__global__ __launch_bounds__(256) void extract_patch_kernel(
    const float* __restrict__ img1,
    const float* __restrict__ img2,
    const int* __restrict__ matches,
    float* __restrict__ out)
{
    // one 289-float transpose buffer per wave (4 waves / 256-thread block)
    __shared__ float lds[4][NPATCH + 3];   // +3 pad -> 292 floats, 4.7 KB/block

    const int tid   = blockIdx.x * blockDim.x + threadIdx.x;
    const int wave  = tid >> 6;            // global wave id: 0 .. 65535
    const int lane  = tid & 63;
    const int wslot = threadIdx.x >> 6;    // wave slot within block: 0..3
    const int pair  = wave >> 1;           // b*4096 + n : 0 .. 32767
    const int which = wave & 1;            // 0 -> img1, 1 -> img2

    // match coords (wave-uniform)
    const int* m = matches + pair * 4;
    const int mx = m[which ? 2 : 0];
    const int my = m[which ? 3 : 1];

    const int b = pair >> 12;              // pair / 4096
    const float* __restrict__ imgb =
        (which ? img2 : img1) + (size_t)b * (IMG_H * IMG_W);

    // ---- Phase 1: COALESCED gather, image-row order: t = a*17 + c ----
    // a = row offset (slow), c = col offset (fast -> contiguous addresses).
    // Consecutive lanes read consecutive floats of the same image row.
    float sum = 0.f, sumsq = 0.f;
#pragma unroll
    for (int k = 0; k < 5; ++k) {
        const int t = lane + (k << 6);
        float val = 0.f;
        if (t < NPATCH) {
            const int a  = t / DPATCH;          // magic-mul, cheap
            const int c  = t - a * DPATCH;
            const int iy = my + a - RAD;
            const int ix = mx + c - RAD;
            if ((unsigned)iy < IMG_H && (unsigned)ix < IMG_W) {
                val = imgb[iy * IMG_W + ix];
            }
            lds[wslot][t] = val;                // stride-1 LDS write, conflict-free
        }
        sum   += val;                           // mean/var are order-independent
        sumsq += val * val;
    }

    // wave-64 butterfly reduction
#pragma unroll
    for (int off = 32; off > 0; off >>= 1) {
        sum   += __shfl_xor(sum,   off, 64);
        sumsq += __shfl_xor(sumsq, off, 64);
    }

    const float mean = sum * (1.0f / 289.0f);
    float var = (sumsq - 289.0f * mean * mean) * (1.0f / 288.0f);
    var = fmaxf(var, 0.0f);
    const float inv = 1.0f / (sqrtf(var) + 1e-4f);

    // drain LDS writes (cheap: one barrier per block; waves are in lockstep)
    __syncthreads();

    // ---- Phase 2: transposed LDS read, COALESCED output write ----
    // output j needs (a = j%17, c = j/17) -> lds index a*17 + c.
    // Lane-to-lane LDS stride = 17 (odd) -> spreads over all 32 banks, <=2-way (free).
    float* __restrict__ o = out + (size_t)pair * 578 + which * NPATCH;
#pragma unroll
    for (int k = 0; k < 5; ++k) {
        const int j = lane + (k << 6);
        if (j < NPATCH) {
            const int c = j / DPATCH;
            const int a = j - c * DPATCH;       // j % 17
            const float val = lds[wslot][a * DPATCH + c];
            // streamed-once output: don't pollute L2/LLC (keep it for the images)
            __builtin_nontemporal_store((val - mean) * inv, &o[j]);
        }
    }
}

extern "C" void kernel_launch(void* const* d_in, const int* in_sizes, int n_in,
                              void* d_out, int out_size, void* d_ws, size_t ws_size,
                              hipStream_t stream) {
    const float* img1  = (const float*)d_in[0];
    const float* img2  = (const float*)d_in[1];
    const int* matches = (const int*)d_in[2];
    float* out         = (float*)d_out;

    // 8 * 4096 pairs * 2 images = 65536 waves; 4 waves (patches) per block
    const int n_waves = 8 * 4096 * 2;
    dim3 block(256);
    dim3 grid(n_waves * 64 / 256);
    hipLaunchKernelGGL(extract_patch_kernel, grid, block, 0, stream,
                       img1, img2, matches, out);
}

// Round 2
// 141.594 us; speedup vs baseline: 1.0769x; 1.0388x over previous
//
#include <hip/hip_runtime.h>

// Problem: B=8, H=W=1024, N=4096 matches, R=8 -> d=17, patch=289, out (B,N,578) f32.
// p[b,n,j] = img[b, m_y + j%17 - 8, m_x + j/17 - 8]   (zero-pad OOB)
// normalize each 289-vector: (p - mean) / (std_ddof1 + 1e-4)
//
// R1 post-mortem: kernel is bound by VMEM *instruction count* (fixed ~16clk
// address-processing per divergent wave64 VMEM op) + address VALU, not bytes.
// R2: vectorize everything to dwordx4 -> 2 gather insts + 2 store insts per
// wave (was 5+5), drop the block barrier (per-wave LDS buffer, DS in-order).

#define IMG_H 1024
#define IMG_W 1024
#define DPATCH 17
#define NPATCH 289
#define RAD 8
#define LROW 20   // LDS row stride in floats: 5 float4 chunks, keeps 16B alignment

typedef float float4v __attribute__((ext_vector_type(4)));

__global__ __launch_bounds__(256) void extract_patch_kernel(
    const float* __restrict__ img1,
    const float* __restrict__ img2,
    const int* __restrict__ matches,
    float* __restrict__ out)
{
    // private 17x20-float transpose buffer per wave (1360 B, 4 waves/block)
    __shared__ float lds[4][DPATCH * LROW];

    const int tid   = blockIdx.x * blockDim.x + threadIdx.x;
    const int wave  = tid >> 6;            // 0 .. 65535
    const int lane  = tid & 63;
    const int wslot = threadIdx.x >> 6;    // 0..3
    const int pair  = wave >> 1;           // b*4096 + n
    const int which = wave & 1;            // 0 -> img1, 1 -> img2

    const int* m = matches + pair * 4;     // wave-uniform scalar loads
    const int mx = m[which ? 2 : 0];
    const int my = m[which ? 3 : 1];

    const int b = pair >> 12;
    const float* __restrict__ imgb =
        (which ? img2 : img1) + (size_t)b * (IMG_H * IMG_W);

    float* __restrict__ lrow = &lds[wslot][0];

    // ---- Phase 1: gather 17 rows x 5 float4-chunks = 85 slots, 2 insts ----
    // slot s: row a = s/5, chunk q = s%5, image cols cb..cb+3 = mx-8+4q ...
    float sum = 0.f, sumsq = 0.f;
#pragma unroll
    for (int k = 0; k < 2; ++k) {
        const int s = lane + (k << 6);
        if (s < 85) {
            const int a  = s / 5;              // magic-mul div
            const int q  = s - a * 5;
            const int iy = my + a - RAD;
            const int cb = mx + (q << 2) - RAD;
            float4v vv = {0.f, 0.f, 0.f, 0.f};
            const bool rowok = ((unsigned)iy < IMG_H);
            if (rowok && cb >= 0 && (cb + 3) < IMG_W) {
                // fast path: one dwordx4 (4B-aligned; gfx950 global supports)
                float4v t = *(const float4v*)(imgb + iy * IMG_W + cb);
                // mask patch-cols > 16 (only chunk q=4, elems 1..3)
                vv.x = t.x;
                vv.y = (q < 4) ? t.y : 0.f;
                vv.z = (q < 4) ? t.z : 0.f;
                vv.w = (q < 4) ? t.w : 0.f;
            } else if (rowok) {
                // image col-edge (~2% of patches): masked scalar loads
                const float* rp = imgb + iy * IMG_W;
#pragma unroll
                for (int e = 0; e < 4; ++e) {
                    const int cp = (q << 2) + e;    // patch col
                    const int ix = cb + e;          // image col
                    float v = 0.f;
                    if (cp <= 16 && (unsigned)ix < IMG_W) v = rp[ix];
                    ((float*)&vv)[e] = v;
                }
            }
            *(float4v*)(lrow + a * LROW + (q << 2)) = vv;   // 16B-aligned
            sum   += (vv.x + vv.y) + (vv.z + vv.w);
            sumsq += (vv.x * vv.x + vv.y * vv.y) + (vv.z * vv.z + vv.w * vv.w);
        }
    }

    // wave-64 butterfly reduction (order-independent stats)
#pragma unroll
    for (int off = 32; off > 0; off >>= 1) {
        sum   += __shfl_xor(sum,   off, 64);
        sumsq += __shfl_xor(sumsq, off, 64);
    }

    const float mean = sum * (1.0f / 289.0f);
    float var = (sumsq - 289.0f * mean * mean) * (1.0f / 288.0f);
    var = fmaxf(var, 0.0f);
    const float inv = 1.0f / (sqrtf(var) + 1e-4f);

    // NO __syncthreads: buffer is wave-private and DS ops from one wave
    // execute in order -> the transposed reads below see our writes.

    // ---- Phase 2: transposed LDS read, wide coalesced store ----
    // out[j] = patch[row = j%17][col = j/17] = lrow[(j%17)*LROW + j/17]
    float* __restrict__ o = out + (size_t)pair * 578 + which * NPATCH;

    {   // j = 4*lane + e, e = 0..3  -> one dwordx4 store
        const int j0 = lane << 2;
        int c = j0 / DPATCH;               // magic-mul div, once per lane
        int a = j0 - c * DPATCH;
        float4v st;
#pragma unroll
        for (int e = 0; e < 4; ++e) {
            ((float*)&st)[e] = (lrow[a * LROW + c] - mean) * inv;
            ++a;
            if (a == DPATCH) { a = 0; ++c; }   // incremental j%17, j/17
        }
        __builtin_nontemporal_store(st, (float4v*)(o + j0));
    }
    if (lane < NPATCH - 256) {             // tail: j = 256 + lane (33 lanes)
        const int j = 256 + lane;
        const int c = j / DPATCH;
        const int a = j - c * DPATCH;
        __builtin_nontemporal_store((lrow[a * LROW + c] - mean) * inv, o + j);
    }
}

extern "C" void kernel_launch(void* const* d_in, const int* in_sizes, int n_in,
                              void* d_out, int out_size, void* d_ws, size_t ws_size,
                              hipStream_t stream) {
    const float* img1  = (const float*)d_in[0];
    const float* img2  = (const float*)d_in[1];
    const int* matches = (const int*)d_in[2];
    float* out         = (float*)d_out;

    const int n_waves = 8 * 4096 * 2;      // 65536 waves, 1 per (patch, image)
    dim3 block(256);
    dim3 grid(n_waves * 64 / 256);
    hipLaunchKernelGGL(extract_patch_kernel, grid, block, 0, stream,
                       img1, img2, matches, out);
}

// Round 4
// 138.493 us; speedup vs baseline: 1.1010x; 1.0224x over previous
//
#include <hip/hip_runtime.h>

// B=8, H=W=1024, N=4096, R=8 -> d=17, patch=289, out (B,N,578) f32.
// p1[b,n,j] = img1[b, m1 + j%17 - 8, m0 + j/17 - 8]; p2 likewise with (m2,m3).
// normalize each 289-vector: (p - mean) / (std_ddof1 + 1e-4).
//
// R3 postmortem: tail bug — 578-512=66 elements > 64 lanes, j=576/577 never
// written. R4 = R3 with the tail stored as 33 lanes x dwordx2 (8B aligned).

#define IMG_H 1024
#define IMG_W 1024
#define DPATCH 17
#define NPATCH 289
#define RAD 8
#define LROW 20               // LDS row stride (5 float4 chunks, 16B aligned)
#define PLANE (DPATCH * LROW) // 340 floats per patch plane

typedef float float4v __attribute__((ext_vector_type(4)));
typedef float float2v __attribute__((ext_vector_type(2)));

__global__ __launch_bounds__(256) void extract_patch_kernel(
    const float* __restrict__ img1,
    const float* __restrict__ img2,
    const int* __restrict__ matches,
    float* __restrict__ out)
{
    // per-wave private transpose buffer: 2 patch planes (2720 B), 4 waves/block
    __shared__ float lds[4][2 * PLANE];

    const int lane  = threadIdx.x & 63;
    // force wave-uniform -> SGPR, so matches read compiles to s_load_dwordx4
    const int wslot = __builtin_amdgcn_readfirstlane(threadIdx.x >> 6);
    const int pair  = blockIdx.x * 4 + wslot;   // b*4096 + n, scalar
    const int b     = pair >> 12;               // scalar

    const int4 mm = *(const int4*)(matches + (size_t)pair * 4); // scalar load
    const int mx1 = mm.x, my1 = mm.y, mx2 = mm.z, my2 = mm.w;

    const size_t ioff = (size_t)b * (IMG_H * IMG_W);
    const float* __restrict__ imgb1 = img1 + ioff;
    const float* __restrict__ imgb2 = img2 + ioff;

    float* __restrict__ lbase = &lds[wslot][0];

    float sA = 0.f, qA = 0.f, sB = 0.f, qB = 0.f;

    // gather one slot u = a*5 + q of one patch: image row my+a-8, cols mx+4q-8..+3
    auto gather = [&](int u, const float* __restrict__ imgp, int mx, int my,
                      float* __restrict__ ldst, float& ssum, float& ssq) {
        const int a  = u / 5;                 // magic-mul
        const int q  = u - a * 5;
        const int iy = my + a - RAD;
        const int cb = mx + (q << 2) - RAD;
        float4v vv = {0.f, 0.f, 0.f, 0.f};
        const bool rowok = ((unsigned)iy < IMG_H);
        if (rowok && cb >= 0 && (cb + 3) < IMG_W) {
            float4v t = *(const float4v*)(imgp + iy * IMG_W + cb);
            vv.x = t.x;
            vv.y = (q < 4) ? t.y : 0.f;       // mask patch-cols > 16 (chunk q=4)
            vv.z = (q < 4) ? t.z : 0.f;
            vv.w = (q < 4) ? t.w : 0.f;
        } else if (rowok) {                   // image col-edge (~2% of patches)
            const float* rp = imgp + iy * IMG_W;
#pragma unroll
            for (int e = 0; e < 4; ++e) {
                const int cp = (q << 2) + e;  // patch col
                const int ix = cb + e;        // image col
                float v = 0.f;
                if (cp <= 16 && (unsigned)ix < IMG_W) v = rp[ix];
                ((float*)&vv)[e] = v;
            }
        }
        *(float4v*)(ldst + a * LROW + (q << 2)) = vv;   // 16B-aligned LDS write
        ssum += (vv.x + vv.y) + (vv.z + vv.w);
        ssq  += (vv.x * vv.x + vv.y * vv.y) + (vv.z * vv.z + vv.w * vv.w);
    };

    // ---- Phase 1: 170 slots over 3 iters (89% lane efficiency) ----
    // iter0: slots 0..63   -> patch1 u=0..63
    gather(lane, imgb1, mx1, my1, lbase, sA, qA);

    // iter1: slots 64..127 -> patch1 u=64..84 (lanes 0..20), patch2 u=0..42
    {
        const int s  = 64 + lane;
        const bool w2 = (s >= 85);
        const int u  = w2 ? s - 85 : s;
        const float* imgp = w2 ? imgb2 : imgb1;
        const int mx = w2 ? mx2 : mx1;
        const int my = w2 ? my2 : my1;
        float ss = 0.f, sq = 0.f;
        gather(u, imgp, mx, my, lbase + (w2 ? PLANE : 0), ss, sq);
        if (w2) { sB += ss; qB += sq; } else { sA += ss; qA += sq; }
    }

    // iter2: slots 128..169 -> patch2 u=43..84 (lanes 0..41)
    if (lane < 42) {
        gather(43 + lane, imgb2, mx2, my2, lbase + PLANE, sB, qB);
    }

    // ---- wave-64 butterfly reduction, both patches (order-independent) ----
#pragma unroll
    for (int off = 32; off > 0; off >>= 1) {
        sA += __shfl_xor(sA, off, 64);
        qA += __shfl_xor(qA, off, 64);
        sB += __shfl_xor(sB, off, 64);
        qB += __shfl_xor(qB, off, 64);
    }

    const float meanA = sA * (1.0f / 289.0f);
    float varA = (qA - 289.0f * meanA * meanA) * (1.0f / 288.0f);
    varA = fmaxf(varA, 0.0f);
    const float invA = 1.0f / (sqrtf(varA) + 1e-4f);

    const float meanB = sB * (1.0f / 289.0f);
    float varB = (qB - 289.0f * meanB * meanB) * (1.0f / 288.0f);
    varB = fmaxf(varB, 0.0f);
    const float invB = 1.0f / (sqrtf(varB) + 1e-4f);

    // NO barrier: buffer is wave-private, DS ops from one wave are in-order.

    // ---- Phase 2: transposed LDS read, coalesced wide stores (578 floats) ----
    // out[j]: which = j>=289; jj = j - 289*which; val = plane[(jj%17)*20 + jj/17]
    float* __restrict__ o = out + (size_t)pair * 578;
#pragma unroll
    for (int k = 0; k < 2; ++k) {
        const int j0 = (k << 8) + (lane << 2);   // 0..511
        float4v st;
#pragma unroll
        for (int e = 0; e < 4; ++e) {
            const int j   = j0 + e;
            const bool w2 = (j >= NPATCH);
            const int jj  = w2 ? j - NPATCH : j;
            const int c   = jj / DPATCH;          // magic-mul
            const int a   = jj - c * DPATCH;
            const float v = lbase[(w2 ? PLANE : 0) + a * LROW + c];
            ((float*)&st)[e] = (v - (w2 ? meanB : meanA)) * (w2 ? invB : invA);
        }
        __builtin_nontemporal_store(st, (float4v*)(o + j0));
    }
    // tail j = 512..577: 66 elements = 33 lanes x dwordx2 (8B-aligned:
    // 578*4 = 2312 = 0 mod 8, (512 + 2*lane)*4 = 0 mod 8)
    if (lane < 33) {
        const int j0 = 512 + (lane << 1);
        float2v st;
#pragma unroll
        for (int e = 0; e < 2; ++e) {
            const int jj = j0 + e - NPATCH;       // all patch2 (512 >= 289)
            const int c  = jj / DPATCH;
            const int a  = jj - c * DPATCH;
            ((float*)&st)[e] = (lbase[PLANE + a * LROW + c] - meanB) * invB;
        }
        __builtin_nontemporal_store(st, (float2v*)(o + j0));
    }
}

extern "C" void kernel_launch(void* const* d_in, const int* in_sizes, int n_in,
                              void* d_out, int out_size, void* d_ws, size_t ws_size,
                              hipStream_t stream) {
    const float* img1  = (const float*)d_in[0];
    const float* img2  = (const float*)d_in[1];
    const int* matches = (const int*)d_in[2];
    float* out         = (float*)d_out;

    // one wave per (b,n) pair: 8*4096 = 32768 waves, 4 waves/block
    const int n_pairs = 8 * 4096;
    dim3 block(256);
    dim3 grid(n_pairs / 4);
    hipLaunchKernelGGL(extract_patch_kernel, grid, block, 0, stream,
                       img1, img2, matches, out);
}